// Round 1
// baseline (701.394 us; speedup 1.0000x reference)
//
#include <hip/hip_runtime.h>
#include <hip/hip_bf16.h>

// ---------------------------------------------------------------------------
// Problem: WrapperModel_53240414601491
// image [8192,8192] f32 -> crop-bounds -> bilinear 256x256 -> invert ->
// dilated 3x3 ones conv (rhs_dilation=2, SAME) -> clip/invert ->
// 5x (conv3x3 s2 p1 + BN(eval) + ReLU): 256->128->64->32->16->8, C: 1->64->64..
// -> global avg pool -> head [2,64] -> argmax label (written as float 0/1).
// ---------------------------------------------------------------------------

#define IMG_H 8192
#define IMG_W 8192
#define EPS 1e-5f

// ---------------------------------------------------------------------------
// Kernel 1: crop bounds via edge-inward early-exit scans.
// block 0: top row, block 1: bottom row, block 2: left col, block 3: right col.
// A row/col is "whitespace" iff all elements equal (min==max, no NaN in input).
// Equivalent lazy form: non-constant iff exists element != element[0].
// ---------------------------------------------------------------------------
__device__ __forceinline__ int scan_nonconst(const float* __restrict__ base,
                                             int n, long stride, int* sflag) {
  const int tid = threadIdx.x;
  const float ref = base[0];
  for (int start = 0; start < n; start += 1024) {
    if (tid == 0) *sflag = 0;
    __syncthreads();
    int f = 0;
#pragma unroll
    for (int u = 0; u < 4; ++u) {
      const int k = start + u * 256 + tid;
      if (k < n && base[(long)k * stride] != ref) f = 1;
    }
    if (f) *sflag = 1;  // benign race
    __syncthreads();
    if (*sflag) return 1;  // uniform read after barrier
  }
  return 0;
}

__global__ __launch_bounds__(256) void crop_bounds_k(
    const float* __restrict__ img, int* __restrict__ bounds) {
  __shared__ int sflag;
  const int dir = blockIdx.x;
  if (dir == 0) {  // top: first non-constant row
    for (int r = 0; r < IMG_H; ++r)
      if (scan_nonconst(img + (long)r * IMG_W, IMG_W, 1, &sflag)) {
        if (threadIdx.x == 0) bounds[0] = r;
        return;
      }
    if (threadIdx.x == 0) bounds[0] = 0;
  } else if (dir == 1) {  // bottom: last non-constant row
    for (int r = IMG_H - 1; r >= 0; --r)
      if (scan_nonconst(img + (long)r * IMG_W, IMG_W, 1, &sflag)) {
        if (threadIdx.x == 0) bounds[1] = r;
        return;
      }
    if (threadIdx.x == 0) bounds[1] = IMG_H - 1;
  } else if (dir == 2) {  // left: first non-constant col
    for (int c = 0; c < IMG_W; ++c)
      if (scan_nonconst(img + c, IMG_H, IMG_W, &sflag)) {
        if (threadIdx.x == 0) bounds[2] = c;
        return;
      }
    if (threadIdx.x == 0) bounds[2] = 0;
  } else {  // right: last non-constant col
    for (int c = IMG_W - 1; c >= 0; --c)
      if (scan_nonconst(img + c, IMG_H, IMG_W, &sflag)) {
        if (threadIdx.x == 0) bounds[3] = c;
        return;
      }
    if (threadIdx.x == 0) bounds[3] = IMG_W - 1;
  }
}

// ---------------------------------------------------------------------------
// Kernel 2: fused crop + bilinear resize (align_corners=False) + invert.
// im[i][j] = 255 - resized[i][j]. grid: 256 blocks (rows) x 256 threads (cols)
// ---------------------------------------------------------------------------
__global__ __launch_bounds__(256) void resize_invert_k(
    const float* __restrict__ img, const int* __restrict__ bounds,
    float* __restrict__ im) {
  const int i = blockIdx.x;
  const int j = threadIdx.x;
  const int t = bounds[0], b = bounds[1], l = bounds[2], r = bounds[3];
  const float sy = (float)(b - t + 1);
  const float sx = (float)(r - l + 1);
  const float cy = (float)t + ((float)i + 0.5f) * sy / 256.0f - 0.5f;
  const float cx = (float)l + ((float)j + 0.5f) * sx / 256.0f - 0.5f;
  const float cy0 = floorf(cy), cx0 = floorf(cx);
  const float wy = cy - cy0, wx = cx - cx0;
  const int y0 = (int)fminf(fmaxf(cy0, (float)t), (float)b);
  const int y1 = (int)fminf(fmaxf(cy0 + 1.0f, (float)t), (float)b);
  const int x0 = (int)fminf(fmaxf(cx0, (float)l), (float)r);
  const int x1 = (int)fminf(fmaxf(cx0 + 1.0f, (float)l), (float)r);
  const float v00 = img[(long)y0 * IMG_W + x0];
  const float v01 = img[(long)y0 * IMG_W + x1];
  const float v10 = img[(long)y1 * IMG_W + x0];
  const float v11 = img[(long)y1 * IMG_W + x1];
  const float top_row = v00 * (1.0f - wx) + v01 * wx;
  const float bot_row = v10 * (1.0f - wx) + v11 * wx;
  const float res = top_row * (1.0f - wy) + bot_row * wy;
  im[i * 256 + j] = 255.0f - res;
}

// ---------------------------------------------------------------------------
// Kernel 3: dilated 3x3 ones conv (taps at -2,0,+2, zero pad) + clip + invert
// ---------------------------------------------------------------------------
__global__ __launch_bounds__(256) void dilate_invert_k(
    const float* __restrict__ im, float* __restrict__ out) {
  const int i = blockIdx.x;
  const int j = threadIdx.x;
  float s = 0.0f;
#pragma unroll
  for (int dy = -2; dy <= 2; dy += 2) {
    const int y = i + dy;
    if ((unsigned)y >= 256u) continue;
#pragma unroll
    for (int dx = -2; dx <= 2; dx += 2) {
      const int x = j + dx;
      if ((unsigned)x >= 256u) continue;
      s += im[y * 256 + x];
    }
  }
  out[i * 256 + j] = 255.0f - fminf(fmaxf(s, 0.0f), 255.0f);
}

// ---------------------------------------------------------------------------
// Kernel 4: generic conv3x3 stride2 pad1 + bias + BN(eval) + ReLU.
// Each thread computes one output pixel for 8 consecutive output channels.
// Weights for the block's 8 ocs staged in LDS (<= 8*64*9 floats = 18 KB).
// grid: (ceil(OW/16), ceil(OH/16), OC/8), block 256 = 16x16 spatial tile.
// ---------------------------------------------------------------------------
__global__ __launch_bounds__(256) void conv_bn_relu_k(
    const float* __restrict__ in, const float* __restrict__ wt,
    const float* __restrict__ bias, const float* __restrict__ gamma,
    const float* __restrict__ beta, const float* __restrict__ mean,
    const float* __restrict__ var, float* __restrict__ out,
    int IC, int IH, int IW, int OH, int OW) {
  __shared__ float wl[8 * 64 * 9];
  const int ocg = blockIdx.z * 8;
  const int nW = 8 * IC * 9;
  for (int idx = threadIdx.x; idx < nW; idx += 256)
    wl[idx] = wt[(long)ocg * IC * 9 + idx];
  __syncthreads();

  const int ox = blockIdx.x * 16 + (threadIdx.x & 15);
  const int oy = blockIdx.y * 16 + (threadIdx.x >> 4);
  if (ox >= OW || oy >= OH) return;

  float acc[8];
#pragma unroll
  for (int o = 0; o < 8; ++o) acc[o] = 0.0f;

  const int iy0 = 2 * oy - 1;
  const int ix0 = 2 * ox - 1;
  for (int ic = 0; ic < IC; ++ic) {
    const float* __restrict__ ip = in + (long)ic * IH * IW;
    const float* __restrict__ wp = wl + ic * 9;
#pragma unroll
    for (int ky = 0; ky < 3; ++ky) {
      const int iy = iy0 + ky;
      if ((unsigned)iy >= (unsigned)IH) continue;
#pragma unroll
      for (int kx = 0; kx < 3; ++kx) {
        const int ix = ix0 + kx;
        if ((unsigned)ix >= (unsigned)IW) continue;
        const float v = ip[(long)iy * IW + ix];
        const int t = ky * 3 + kx;
#pragma unroll
        for (int o = 0; o < 8; ++o)
          acc[o] = fmaf(v, wp[o * IC * 9 + t], acc[o]);
      }
    }
  }

#pragma unroll
  for (int o = 0; o < 8; ++o) {
    const int oc = ocg + o;
    const float s = gamma[oc] / sqrtf(var[oc] + EPS);
    const float v = (acc[o] + bias[oc] - mean[oc]) * s + beta[oc];
    out[((long)oc * OH + oy) * OW + ox] = fmaxf(v, 0.0f);
  }
}

// ---------------------------------------------------------------------------
// Kernel 5: global average pool [64][8][8] -> head [2,64] -> argmax -> float
// one wave (64 threads); thread c owns channel c.
// ---------------------------------------------------------------------------
__global__ __launch_bounds__(64) void head_argmax_k(
    const float* __restrict__ x, const float* __restrict__ hw,
    const float* __restrict__ hb, float* __restrict__ out) {
  const int c = threadIdx.x;
  float s = 0.0f;
#pragma unroll
  for (int k = 0; k < 64; ++k) s += x[c * 64 + k];
  const float feat = s * (1.0f / 64.0f);
  float p0 = feat * hw[c];        // head_w[0][c]
  float p1 = feat * hw[64 + c];   // head_w[1][c]
#pragma unroll
  for (int off = 32; off > 0; off >>= 1) {
    p0 += __shfl_down(p0, off);
    p1 += __shfl_down(p1, off);
  }
  if (c == 0) {
    const float l0 = p0 + hb[0];
    const float l1 = p1 + hb[1];
    out[0] = (l1 > l0) ? 1.0f : 0.0f;  // argmax, ties -> 0
  }
}

// ---------------------------------------------------------------------------
extern "C" void kernel_launch(void* const* d_in, const int* in_sizes, int n_in,
                              void* d_out, int out_size, void* d_ws,
                              size_t ws_size, hipStream_t stream) {
  const float* image   = (const float*)d_in[0];
  const float* conv0_w = (const float*)d_in[1];
  const float* conv0_b = (const float*)d_in[2];
  const float* convs_w = (const float*)d_in[3];  // [4][64][64][3][3]
  const float* convs_b = (const float*)d_in[4];  // [4][64]
  const float* bn_g    = (const float*)d_in[5];  // [5][64]
  const float* bn_b    = (const float*)d_in[6];
  const float* bn_m    = (const float*)d_in[7];
  const float* bn_v    = (const float*)d_in[8];
  const float* head_w  = (const float*)d_in[9];  // [2][64]
  const float* head_b  = (const float*)d_in[10]; // [2]

  // workspace layout (floats); total ~1.47M floats ~= 5.9 MB
  float* W = (float*)d_ws;
  int* bounds = (int*)d_ws;          // 4 ints
  float* im = W + 16;                // 256*256
  float* x1 = im + 65536;            // 256*256
  float* c0 = x1 + 65536;            // 64*128*128
  float* c1 = c0 + 1048576;          // 64*64*64
  float* c2 = c1 + 262144;           // 64*32*32
  float* c3 = c2 + 65536;            // 64*16*16
  float* c4 = c3 + 16384;            // 64*8*8

  crop_bounds_k<<<4, 256, 0, stream>>>(image, bounds);
  resize_invert_k<<<256, 256, 0, stream>>>(image, bounds, im);
  dilate_invert_k<<<256, 256, 0, stream>>>(im, x1);

  // conv0: 1 -> 64, 256 -> 128
  conv_bn_relu_k<<<dim3(8, 8, 8), 256, 0, stream>>>(
      x1, conv0_w, conv0_b, bn_g, bn_b, bn_m, bn_v, c0, 1, 256, 256, 128, 128);
  // conv1: 64 -> 64, 128 -> 64
  conv_bn_relu_k<<<dim3(4, 4, 8), 256, 0, stream>>>(
      c0, convs_w + 0 * 36864, convs_b + 0 * 64, bn_g + 64, bn_b + 64,
      bn_m + 64, bn_v + 64, c1, 64, 128, 128, 64, 64);
  // conv2: 64 -> 64, 64 -> 32
  conv_bn_relu_k<<<dim3(2, 2, 8), 256, 0, stream>>>(
      c1, convs_w + 1 * 36864, convs_b + 1 * 64, bn_g + 128, bn_b + 128,
      bn_m + 128, bn_v + 128, c2, 64, 64, 64, 32, 32);
  // conv3: 64 -> 64, 32 -> 16
  conv_bn_relu_k<<<dim3(1, 1, 8), 256, 0, stream>>>(
      c2, convs_w + 2 * 36864, convs_b + 2 * 64, bn_g + 192, bn_b + 192,
      bn_m + 192, bn_v + 192, c3, 64, 32, 32, 16, 16);
  // conv4: 64 -> 64, 16 -> 8
  conv_bn_relu_k<<<dim3(1, 1, 8), 256, 0, stream>>>(
      c3, convs_w + 3 * 36864, convs_b + 3 * 64, bn_g + 256, bn_b + 256,
      bn_m + 256, bn_v + 256, c4, 64, 16, 16, 8, 8);

  head_argmax_k<<<1, 64, 0, stream>>>(c4, head_w, head_b, (float*)d_out);
}

// Round 2
// 629.812 us; speedup vs baseline: 1.1137x; 1.1137x over previous
//
#include <hip/hip_runtime.h>
#include <hip/hip_bf16.h>

// ---------------------------------------------------------------------------
// WrapperModel_53240414601491
// image [8192,8192] f32 -> crop-bounds -> bilinear 256x256 + invert ->
// dilated 3x3 ones conv (rhs_dilation=2, SAME) + clip + invert ->
// 5x (conv3x3 s2 p1 + BN(eval) + ReLU): 256->128->64->32->16->8, C: 1->64 ...
// -> global avg pool -> head [2,64] -> argmax label (float 0/1).
// ---------------------------------------------------------------------------

#define IMG_H 8192
#define IMG_W 8192
#define EPS 1e-5f

// ---------------------------------------------------------------------------
// Kernel 1: crop bounds via edge-inward early-exit scans.
// block 0: top row, 1: bottom row, 2: left col, 3: right col.
// non-constant iff exists element != element[0]  (== min!=max for real data)
// ---------------------------------------------------------------------------
__device__ __forceinline__ int scan_nonconst(const float* __restrict__ base,
                                             int n, long stride, int* sflag) {
  const int tid = threadIdx.x;
  const float ref = base[0];
  for (int start = 0; start < n; start += 1024) {
    if (tid == 0) *sflag = 0;
    __syncthreads();
    int f = 0;
#pragma unroll
    for (int u = 0; u < 4; ++u) {
      const int k = start + u * 256 + tid;
      if (k < n && base[(long)k * stride] != ref) f = 1;
    }
    if (f) *sflag = 1;  // benign race
    __syncthreads();
    if (*sflag) return 1;
  }
  return 0;
}

__global__ __launch_bounds__(256) void crop_bounds_k(
    const float* __restrict__ img, int* __restrict__ bounds) {
  __shared__ int sflag;
  const int dir = blockIdx.x;
  if (dir == 0) {
    for (int r = 0; r < IMG_H; ++r)
      if (scan_nonconst(img + (long)r * IMG_W, IMG_W, 1, &sflag)) {
        if (threadIdx.x == 0) bounds[0] = r;
        return;
      }
    if (threadIdx.x == 0) bounds[0] = 0;
  } else if (dir == 1) {
    for (int r = IMG_H - 1; r >= 0; --r)
      if (scan_nonconst(img + (long)r * IMG_W, IMG_W, 1, &sflag)) {
        if (threadIdx.x == 0) bounds[1] = r;
        return;
      }
    if (threadIdx.x == 0) bounds[1] = IMG_H - 1;
  } else if (dir == 2) {
    for (int c = 0; c < IMG_W; ++c)
      if (scan_nonconst(img + c, IMG_H, IMG_W, &sflag)) {
        if (threadIdx.x == 0) bounds[2] = c;
        return;
      }
    if (threadIdx.x == 0) bounds[2] = 0;
  } else {
    for (int c = IMG_W - 1; c >= 0; --c)
      if (scan_nonconst(img + c, IMG_H, IMG_W, &sflag)) {
        if (threadIdx.x == 0) bounds[3] = c;
        return;
      }
    if (threadIdx.x == 0) bounds[3] = IMG_W - 1;
  }
}

// ---------------------------------------------------------------------------
// Kernel 2 (fused): crop+bilinear resize+invert, then dilated 3x3 ones conv
// (taps -2/0/+2, zero pad) + clip + invert. Block i = output row i; LDS holds
// inverted-resize rows {i-2, i, i+2}. Bitwise identical to the 2-kernel form.
// ---------------------------------------------------------------------------
__global__ __launch_bounds__(256) void resize_dilate_k(
    const float* __restrict__ img, const int* __restrict__ bounds,
    float* __restrict__ out) {
  __shared__ float s[3][256];
  const int i = blockIdx.x;
  const int j = threadIdx.x;
  const int tb = bounds[0], bb = bounds[1], lb = bounds[2], rb = bounds[3];
  const float sy = (float)(bb - tb + 1);
  const float sx = (float)(rb - lb + 1);

  // x sampling for column j (same for all rows)
  const float cx = (float)lb + ((float)j + 0.5f) * sx / 256.0f - 0.5f;
  const float cx0 = floorf(cx);
  const float wx = cx - cx0;
  const int x0 = (int)fminf(fmaxf(cx0, (float)lb), (float)rb);
  const int x1 = (int)fminf(fmaxf(cx0 + 1.0f, (float)lb), (float)rb);

#pragma unroll
  for (int k = 0; k < 3; ++k) {
    const int row = i + 2 * (k - 1);
    float v = 0.0f;
    if ((unsigned)row < 256u) {
      const float cy = (float)tb + ((float)row + 0.5f) * sy / 256.0f - 0.5f;
      const float cy0 = floorf(cy);
      const float wy = cy - cy0;
      const int y0 = (int)fminf(fmaxf(cy0, (float)tb), (float)bb);
      const int y1 = (int)fminf(fmaxf(cy0 + 1.0f, (float)tb), (float)bb);
      const float v00 = img[(long)y0 * IMG_W + x0];
      const float v01 = img[(long)y0 * IMG_W + x1];
      const float v10 = img[(long)y1 * IMG_W + x0];
      const float v11 = img[(long)y1 * IMG_W + x1];
      const float tr = v00 * (1.0f - wx) + v01 * wx;
      const float br = v10 * (1.0f - wx) + v11 * wx;
      v = 255.0f - (tr * (1.0f - wy) + br * wy);
    }
    s[k][j] = v;
  }
  __syncthreads();

  float sum = 0.0f;
#pragma unroll
  for (int k = 0; k < 3; ++k) {
    const int y = i + 2 * (k - 1);
    if ((unsigned)y >= 256u) continue;
#pragma unroll
    for (int dx = -2; dx <= 2; dx += 2) {
      const int x = j + dx;
      if ((unsigned)x >= 256u) continue;
      sum += s[k][x];
    }
  }
  out[i * 256 + j] = 255.0f - fminf(fmaxf(sum, 0.0f), 255.0f);
}

// ---------------------------------------------------------------------------
// Kernel 3: generic conv3x3 stride2 pad1 + bias + BN(eval) + ReLU.
// OCP output channels per thread (template), 16x16 spatial tile per block.
// grid: (ceil(OW/16), ceil(OH/16), OC/OCP)
// ---------------------------------------------------------------------------
template <int OCP>
__global__ __launch_bounds__(256) void conv_bn_relu_k(
    const float* __restrict__ in, const float* __restrict__ wt,
    const float* __restrict__ bias, const float* __restrict__ gamma,
    const float* __restrict__ beta, const float* __restrict__ mean,
    const float* __restrict__ var, float* __restrict__ out,
    int IC, int IH, int IW, int OH, int OW) {
  __shared__ float wl[OCP * 64 * 9];
  const int ocg = blockIdx.z * OCP;
  const int nW = OCP * IC * 9;
  for (int idx = threadIdx.x; idx < nW; idx += 256)
    wl[idx] = wt[(long)ocg * IC * 9 + idx];
  __syncthreads();

  const int ox = blockIdx.x * 16 + (threadIdx.x & 15);
  const int oy = blockIdx.y * 16 + (threadIdx.x >> 4);
  if (ox >= OW || oy >= OH) return;

  float acc[OCP];
#pragma unroll
  for (int o = 0; o < OCP; ++o) acc[o] = 0.0f;

  const int iy0 = 2 * oy - 1;
  const int ix0 = 2 * ox - 1;
  for (int ic = 0; ic < IC; ++ic) {
    const float* __restrict__ ip = in + (long)ic * IH * IW;
    const float* __restrict__ wp = wl + ic * 9;
#pragma unroll
    for (int ky = 0; ky < 3; ++ky) {
      const int iy = iy0 + ky;
      if ((unsigned)iy >= (unsigned)IH) continue;
#pragma unroll
      for (int kx = 0; kx < 3; ++kx) {
        const int ix = ix0 + kx;
        if ((unsigned)ix >= (unsigned)IW) continue;
        const float v = ip[(long)iy * IW + ix];
        const int t = ky * 3 + kx;
#pragma unroll
        for (int o = 0; o < OCP; ++o)
          acc[o] = fmaf(v, wp[o * IC * 9 + t], acc[o]);
      }
    }
  }

#pragma unroll
  for (int o = 0; o < OCP; ++o) {
    const int oc = ocg + o;
    const float s = gamma[oc] / sqrtf(var[oc] + EPS);
    const float v = (acc[o] + bias[oc] - mean[oc]) * s + beta[oc];
    out[((long)oc * OH + oy) * OW + ox] = fmaxf(v, 0.0f);
  }
}

// ---------------------------------------------------------------------------
// Kernel 4: specialized conv4 (64ch 16x16 -> 64ch 8x8). One block per output
// channel (64 blocks), 64 threads = all 8x8 output pixels.
// ---------------------------------------------------------------------------
__global__ __launch_bounds__(64) void conv4_k(
    const float* __restrict__ in, const float* __restrict__ wt,
    const float* __restrict__ bias, const float* __restrict__ gamma,
    const float* __restrict__ beta, const float* __restrict__ mean,
    const float* __restrict__ var, float* __restrict__ out) {
  __shared__ float wl[64 * 9];
  const int oc = blockIdx.x;
  for (int idx = threadIdx.x; idx < 576; idx += 64)
    wl[idx] = wt[oc * 576 + idx];
  __syncthreads();

  const int ox = threadIdx.x & 7;
  const int oy = threadIdx.x >> 3;
  const int iy0 = 2 * oy - 1;
  const int ix0 = 2 * ox - 1;
  float acc = 0.0f;
  for (int ic = 0; ic < 64; ++ic) {
    const float* __restrict__ ip = in + ic * 256;
    const float* __restrict__ wp = wl + ic * 9;
#pragma unroll
    for (int ky = 0; ky < 3; ++ky) {
      const int iy = iy0 + ky;
      if ((unsigned)iy >= 16u) continue;
#pragma unroll
      for (int kx = 0; kx < 3; ++kx) {
        const int ix = ix0 + kx;
        if ((unsigned)ix >= 16u) continue;
        acc = fmaf(ip[iy * 16 + ix], wp[ky * 3 + kx], acc);
      }
    }
  }
  const float s = gamma[oc] / sqrtf(var[oc] + EPS);
  const float v = (acc + bias[oc] - mean[oc]) * s + beta[oc];
  out[oc * 64 + threadIdx.x] = fmaxf(v, 0.0f);
}

// ---------------------------------------------------------------------------
// Kernel 5: global avg pool [64][8][8] -> head [2,64] -> argmax -> float
// ---------------------------------------------------------------------------
__global__ __launch_bounds__(64) void head_argmax_k(
    const float* __restrict__ x, const float* __restrict__ hw,
    const float* __restrict__ hb, float* __restrict__ out) {
  const int c = threadIdx.x;
  float s = 0.0f;
#pragma unroll
  for (int k = 0; k < 64; ++k) s += x[c * 64 + k];
  const float feat = s * (1.0f / 64.0f);
  float p0 = feat * hw[c];
  float p1 = feat * hw[64 + c];
#pragma unroll
  for (int off = 32; off > 0; off >>= 1) {
    p0 += __shfl_down(p0, off);
    p1 += __shfl_down(p1, off);
  }
  if (c == 0) {
    const float l0 = p0 + hb[0];
    const float l1 = p1 + hb[1];
    out[0] = (l1 > l0) ? 1.0f : 0.0f;
  }
}

// ---------------------------------------------------------------------------
extern "C" void kernel_launch(void* const* d_in, const int* in_sizes, int n_in,
                              void* d_out, int out_size, void* d_ws,
                              size_t ws_size, hipStream_t stream) {
  const float* image   = (const float*)d_in[0];
  const float* conv0_w = (const float*)d_in[1];
  const float* conv0_b = (const float*)d_in[2];
  const float* convs_w = (const float*)d_in[3];  // [4][64][64][3][3]
  const float* convs_b = (const float*)d_in[4];  // [4][64]
  const float* bn_g    = (const float*)d_in[5];  // [5][64]
  const float* bn_b    = (const float*)d_in[6];
  const float* bn_m    = (const float*)d_in[7];
  const float* bn_v    = (const float*)d_in[8];
  const float* head_w  = (const float*)d_in[9];  // [2][64]
  const float* head_b  = (const float*)d_in[10]; // [2]

  // workspace layout (floats)
  float* W = (float*)d_ws;
  int* bounds = (int*)d_ws;          // 4 ints
  float* x1 = W + 16;                // 256*256   (post dilate/invert)
  float* c0 = x1 + 65536;            // 64*128*128
  float* c1 = c0 + 1048576;          // 64*64*64
  float* c2 = c1 + 262144;           // 64*32*32
  float* c3 = c2 + 65536;            // 64*16*16
  float* c4 = c3 + 16384;            // 64*8*8

  crop_bounds_k<<<4, 256, 0, stream>>>(image, bounds);
  resize_dilate_k<<<256, 256, 0, stream>>>(image, bounds, x1);

  // conv0: 1 -> 64, 256 -> 128   (512 blocks)
  conv_bn_relu_k<8><<<dim3(8, 8, 8), 256, 0, stream>>>(
      x1, conv0_w, conv0_b, bn_g, bn_b, bn_m, bn_v, c0, 1, 256, 256, 128, 128);
  // conv1: 64 -> 64, 128 -> 64   (256 blocks, 4 oc/thread)
  conv_bn_relu_k<4><<<dim3(4, 4, 16), 256, 0, stream>>>(
      c0, convs_w + 0 * 36864, convs_b + 0 * 64, bn_g + 64, bn_b + 64,
      bn_m + 64, bn_v + 64, c1, 64, 128, 128, 64, 64);
  // conv2: 64 -> 64, 64 -> 32    (128 blocks, 2 oc/thread)
  conv_bn_relu_k<2><<<dim3(2, 2, 32), 256, 0, stream>>>(
      c1, convs_w + 1 * 36864, convs_b + 1 * 64, bn_g + 128, bn_b + 128,
      bn_m + 128, bn_v + 128, c2, 64, 64, 64, 32, 32);
  // conv3: 64 -> 64, 32 -> 16    (64 blocks, 1 oc/thread)
  conv_bn_relu_k<1><<<dim3(1, 1, 64), 256, 0, stream>>>(
      c2, convs_w + 2 * 36864, convs_b + 2 * 64, bn_g + 192, bn_b + 192,
      bn_m + 192, bn_v + 192, c3, 64, 32, 32, 16, 16);
  // conv4: 64 -> 64, 16 -> 8     (64 blocks x 64 threads, specialized)
  conv4_k<<<64, 64, 0, stream>>>(
      c3, convs_w + 3 * 36864, convs_b + 3 * 64, bn_g + 256, bn_b + 256,
      bn_m + 256, bn_v + 256, c4);

  head_argmax_k<<<1, 64, 0, stream>>>(c4, head_w, head_b, (float*)d_out);
}

// Round 3
// 581.158 us; speedup vs baseline: 1.2069x; 1.0837x over previous
//
#include <hip/hip_runtime.h>
#include <hip/hip_bf16.h>

// ---------------------------------------------------------------------------
// WrapperModel_53240414601491
// image [8192,8192] f32 -> crop-bounds -> bilinear 256x256 + invert ->
// dilated 3x3 ones conv + clip + invert -> 5x (conv3x3 s2 p1 + BN + ReLU)
// -> global avg pool -> head [2,64] -> argmax label (float 0/1).
// Chain: crop(+barrier-init) -> resize_dilate -> conv0 -> conv1 -> fused tail.
// ---------------------------------------------------------------------------

#define IMG_H 8192
#define IMG_W 8192
#define EPS 1e-5f

// ---------------------------------------------------------------------------
// Kernel 1: crop bounds via edge-inward early-exit scans + grid-barrier init.
// ---------------------------------------------------------------------------
__device__ __forceinline__ int scan_nonconst(const float* __restrict__ base,
                                             int n, long stride, int* sflag) {
  const int tid = threadIdx.x;
  const float ref = base[0];
  for (int start = 0; start < n; start += 1024) {
    if (tid == 0) *sflag = 0;
    __syncthreads();
    int f = 0;
#pragma unroll
    for (int u = 0; u < 4; ++u) {
      const int k = start + u * 256 + tid;
      if (k < n && base[(long)k * stride] != ref) f = 1;
    }
    if (f) *sflag = 1;  // benign race
    __syncthreads();
    if (*sflag) return 1;
  }
  return 0;
}

__global__ __launch_bounds__(256) void crop_bounds_k(
    const float* __restrict__ img, int* __restrict__ bounds,
    int* __restrict__ ctr) {
  __shared__ int sflag;
  if (threadIdx.x == 0) ctr[0] = 0;  // re-init grid barrier (ws is re-poisoned)
  const int dir = blockIdx.x;
  if (dir == 0) {
    for (int r = 0; r < IMG_H; ++r)
      if (scan_nonconst(img + (long)r * IMG_W, IMG_W, 1, &sflag)) {
        if (threadIdx.x == 0) bounds[0] = r;
        return;
      }
    if (threadIdx.x == 0) bounds[0] = 0;
  } else if (dir == 1) {
    for (int r = IMG_H - 1; r >= 0; --r)
      if (scan_nonconst(img + (long)r * IMG_W, IMG_W, 1, &sflag)) {
        if (threadIdx.x == 0) bounds[1] = r;
        return;
      }
    if (threadIdx.x == 0) bounds[1] = IMG_H - 1;
  } else if (dir == 2) {
    for (int c = 0; c < IMG_W; ++c)
      if (scan_nonconst(img + c, IMG_H, IMG_W, &sflag)) {
        if (threadIdx.x == 0) bounds[2] = c;
        return;
      }
    if (threadIdx.x == 0) bounds[2] = 0;
  } else {
    for (int c = IMG_W - 1; c >= 0; --c)
      if (scan_nonconst(img + c, IMG_H, IMG_W, &sflag)) {
        if (threadIdx.x == 0) bounds[3] = c;
        return;
      }
    if (threadIdx.x == 0) bounds[3] = IMG_W - 1;
  }
}

// ---------------------------------------------------------------------------
// Kernel 2 (fused): crop+bilinear resize+invert -> dilated 3x3 ones conv
// (taps -2/0/+2, zero pad) + clip + invert. Block i = output row i.
// ---------------------------------------------------------------------------
__global__ __launch_bounds__(256) void resize_dilate_k(
    const float* __restrict__ img, const int* __restrict__ bounds,
    float* __restrict__ out) {
  __shared__ float s[3][256];
  const int i = blockIdx.x;
  const int j = threadIdx.x;
  const int tb = bounds[0], bb = bounds[1], lb = bounds[2], rb = bounds[3];
  const float sy = (float)(bb - tb + 1);
  const float sx = (float)(rb - lb + 1);

  const float cx = (float)lb + ((float)j + 0.5f) * sx / 256.0f - 0.5f;
  const float cx0 = floorf(cx);
  const float wx = cx - cx0;
  const int x0 = (int)fminf(fmaxf(cx0, (float)lb), (float)rb);
  const int x1 = (int)fminf(fmaxf(cx0 + 1.0f, (float)lb), (float)rb);

#pragma unroll
  for (int k = 0; k < 3; ++k) {
    const int row = i + 2 * (k - 1);
    float v = 0.0f;
    if ((unsigned)row < 256u) {
      const float cy = (float)tb + ((float)row + 0.5f) * sy / 256.0f - 0.5f;
      const float cy0 = floorf(cy);
      const float wy = cy - cy0;
      const int y0 = (int)fminf(fmaxf(cy0, (float)tb), (float)bb);
      const int y1 = (int)fminf(fmaxf(cy0 + 1.0f, (float)tb), (float)bb);
      const float v00 = img[(long)y0 * IMG_W + x0];
      const float v01 = img[(long)y0 * IMG_W + x1];
      const float v10 = img[(long)y1 * IMG_W + x0];
      const float v11 = img[(long)y1 * IMG_W + x1];
      const float tr = v00 * (1.0f - wx) + v01 * wx;
      const float br = v10 * (1.0f - wx) + v11 * wx;
      v = 255.0f - (tr * (1.0f - wy) + br * wy);
    }
    s[k][j] = v;
  }
  __syncthreads();

  float sum = 0.0f;
#pragma unroll
  for (int k = 0; k < 3; ++k) {
    const int y = i + 2 * (k - 1);
    if ((unsigned)y >= 256u) continue;
#pragma unroll
    for (int dx = -2; dx <= 2; dx += 2) {
      const int x = j + dx;
      if ((unsigned)x >= 256u) continue;
      sum += s[k][x];
    }
  }
  out[i * 256 + j] = 255.0f - fminf(fmaxf(sum, 0.0f), 255.0f);
}

// ---------------------------------------------------------------------------
// Kernel 3: generic conv3x3 stride2 pad1 + bias + BN(eval) + ReLU.
// ---------------------------------------------------------------------------
template <int OCP>
__global__ __launch_bounds__(256) void conv_bn_relu_k(
    const float* __restrict__ in, const float* __restrict__ wt,
    const float* __restrict__ bias, const float* __restrict__ gamma,
    const float* __restrict__ beta, const float* __restrict__ mean,
    const float* __restrict__ var, float* __restrict__ out,
    int IC, int IH, int IW, int OH, int OW) {
  __shared__ float wl[OCP * 64 * 9];
  const int ocg = blockIdx.z * OCP;
  const int nW = OCP * IC * 9;
  for (int idx = threadIdx.x; idx < nW; idx += 256)
    wl[idx] = wt[(long)ocg * IC * 9 + idx];
  __syncthreads();

  const int ox = blockIdx.x * 16 + (threadIdx.x & 15);
  const int oy = blockIdx.y * 16 + (threadIdx.x >> 4);
  if (ox >= OW || oy >= OH) return;

  float acc[OCP];
#pragma unroll
  for (int o = 0; o < OCP; ++o) acc[o] = 0.0f;

  const int iy0 = 2 * oy - 1;
  const int ix0 = 2 * ox - 1;
  for (int ic = 0; ic < IC; ++ic) {
    const float* __restrict__ ip = in + (long)ic * IH * IW;
    const float* __restrict__ wp = wl + ic * 9;
#pragma unroll
    for (int ky = 0; ky < 3; ++ky) {
      const int iy = iy0 + ky;
      if ((unsigned)iy >= (unsigned)IH) continue;
#pragma unroll
      for (int kx = 0; kx < 3; ++kx) {
        const int ix = ix0 + kx;
        if ((unsigned)ix >= (unsigned)IW) continue;
        const float v = ip[(long)iy * IW + ix];
        const int t = ky * 3 + kx;
#pragma unroll
        for (int o = 0; o < OCP; ++o)
          acc[o] = fmaf(v, wp[o * IC * 9 + t], acc[o]);
      }
    }
  }

#pragma unroll
  for (int o = 0; o < OCP; ++o) {
    const int oc = ocg + o;
    const float s = gamma[oc] / sqrtf(var[oc] + EPS);
    const float v = (acc[o] + bias[oc] - mean[oc]) * s + beta[oc];
    out[((long)oc * OH + oy) * OW + ox] = fmaxf(v, 0.0f);
  }
}

// ---------------------------------------------------------------------------
// Grid barrier: monotonic counter, device-scope. ctr pre-zeroed upstream.
// All 256 blocks must call every barrier (no early returns in the kernel).
// ---------------------------------------------------------------------------
__device__ __forceinline__ void gbar(int* ctr, int target) {
  __syncthreads();
  if (threadIdx.x == 0) {
    __threadfence();
    __hip_atomic_fetch_add(ctr, 1, __ATOMIC_RELEASE, __HIP_MEMORY_SCOPE_AGENT);
    while (__hip_atomic_load(ctr, __ATOMIC_ACQUIRE,
                             __HIP_MEMORY_SCOPE_AGENT) < target)
      __builtin_amdgcn_s_sleep(1);
  }
  __syncthreads();
}

// ---------------------------------------------------------------------------
// Kernel 4 (fused tail): conv2 -> conv3(ic-split 4) -> conv4(ic-split 16)
// -> avgpool+head+argmax. 256 blocks x 256 threads, 5 grid barriers.
// ---------------------------------------------------------------------------
__global__ __launch_bounds__(256) void tail_fused_k(
    const float* __restrict__ c1, const float* __restrict__ convs_w,
    const float* __restrict__ convs_b, const float* __restrict__ bn_g,
    const float* __restrict__ bn_b, const float* __restrict__ bn_m,
    const float* __restrict__ bn_v, const float* __restrict__ head_w,
    const float* __restrict__ head_b, float* __restrict__ c2,
    float* __restrict__ c3, float* __restrict__ c4, float* __restrict__ p3,
    float* __restrict__ p4, int* __restrict__ ctr, float* __restrict__ out) {
  __shared__ float wl[576];
  const int blk = blockIdx.x;
  const int tid = threadIdx.x;

  // ---- stage A: conv2, c1[64][64][64] -> c2[64][32][32] ----
  {
    const int oc = blk >> 2;                 // 4 blocks per oc
    const int pix = (blk & 3) * 256 + tid;   // 0..1023
    const float* wt = convs_w + 36864 + oc * 576;
    for (int idx = tid; idx < 576; idx += 256) wl[idx] = wt[idx];
    __syncthreads();
    const int oy = pix >> 5, ox = pix & 31;
    const int iy0 = 2 * oy - 1, ix0 = 2 * ox - 1;
    float acc = 0.0f;
    for (int ic = 0; ic < 64; ++ic) {
      const float* __restrict__ ip = c1 + ic * 4096;
      const float* __restrict__ wp = wl + ic * 9;
#pragma unroll
      for (int ky = 0; ky < 3; ++ky) {
        const int iy = iy0 + ky;
        if ((unsigned)iy >= 64u) continue;
#pragma unroll
        for (int kx = 0; kx < 3; ++kx) {
          const int ix = ix0 + kx;
          if ((unsigned)ix >= 64u) continue;
          acc = fmaf(ip[iy * 64 + ix], wp[ky * 3 + kx], acc);
        }
      }
    }
    const float s = bn_g[128 + oc] / sqrtf(bn_v[128 + oc] + EPS);
    c2[oc * 1024 + pix] =
        fmaxf((acc + convs_b[64 + oc] - bn_m[128 + oc]) * s + bn_b[128 + oc],
              0.0f);
  }
  gbar(ctr, 256);

  // ---- stage B partial: conv3 ic-split 4, c2 -> p3[icg][oc][256] ----
  {
    const int icg = blk >> 6;  // 0..3
    const int oc = blk & 63;
    const float* wt = convs_w + 2 * 36864 + oc * 576 + icg * 144;
    for (int idx = tid; idx < 144; idx += 256) wl[idx] = wt[idx];
    __syncthreads();
    const int oy = tid >> 4, ox = tid & 15;
    const int iy0 = 2 * oy - 1, ix0 = 2 * ox - 1;
    float acc = 0.0f;
#pragma unroll 4
    for (int i = 0; i < 16; ++i) {
      const float* __restrict__ ip = c2 + (icg * 16 + i) * 1024;
      const float* __restrict__ wp = wl + i * 9;
#pragma unroll
      for (int ky = 0; ky < 3; ++ky) {
        const int iy = iy0 + ky;
        if ((unsigned)iy >= 32u) continue;
#pragma unroll
        for (int kx = 0; kx < 3; ++kx) {
          const int ix = ix0 + kx;
          if ((unsigned)ix >= 32u) continue;
          acc = fmaf(ip[iy * 32 + ix], wp[ky * 3 + kx], acc);
        }
      }
    }
    p3[blk * 256 + tid] = acc;
  }
  gbar(ctr, 512);

  // ---- stage B reduce: c3[64][16][16] = BN(ReLU(sum partials)) ----
  {
    const int g = blk * 256 + tid;
    if (g < 16384) {
      const int oc = g >> 8;
      const float v = p3[g] + p3[g + 16384] + p3[g + 32768] + p3[g + 49152];
      const float s = bn_g[192 + oc] / sqrtf(bn_v[192 + oc] + EPS);
      c3[g] = fmaxf(
          (v + convs_b[128 + oc] - bn_m[192 + oc]) * s + bn_b[192 + oc], 0.0f);
    }
  }
  gbar(ctr, 768);

  // ---- stage C partial: conv4 ic-split 16, c3 -> p4[icg][oc][64] ----
  {
    const int icg = blk >> 4;            // 0..15
    const int ocb = (blk & 15) * 4;      // 4 ocs per block
    const float* wt = convs_w + 3 * 36864;
    for (int idx = tid; idx < 144; idx += 256) {
      const int o = idx / 36, r = idx % 36;
      wl[idx] = wt[(ocb + o) * 576 + icg * 36 + r];
    }
    __syncthreads();
    const int ol = tid >> 6;  // 0..3
    const int pix = tid & 63;
    const int oy = pix >> 3, ox = pix & 7;
    const int iy0 = 2 * oy - 1, ix0 = 2 * ox - 1;
    float acc = 0.0f;
#pragma unroll
    for (int i = 0; i < 4; ++i) {
      const float* __restrict__ ip = c3 + (icg * 4 + i) * 256;
      const float* __restrict__ wp = wl + ol * 36 + i * 9;
#pragma unroll
      for (int ky = 0; ky < 3; ++ky) {
        const int iy = iy0 + ky;
        if ((unsigned)iy >= 16u) continue;
#pragma unroll
        for (int kx = 0; kx < 3; ++kx) {
          const int ix = ix0 + kx;
          if ((unsigned)ix >= 16u) continue;
          acc = fmaf(ip[iy * 16 + ix], wp[ky * 3 + kx], acc);
        }
      }
    }
    p4[blk * 256 + tid] = acc;  // = icg*4096 + oc*64 + pix
  }
  gbar(ctr, 1024);

  // ---- stage C reduce: c4[64][8][8] ----
  {
    const int g = blk * 256 + tid;
    if (g < 4096) {
      const int oc = g >> 6;
      float v = 0.0f;
#pragma unroll
      for (int k = 0; k < 16; ++k) v += p4[g + k * 4096];
      const float s = bn_g[256 + oc] / sqrtf(bn_v[256 + oc] + EPS);
      c4[g] = fmaxf(
          (v + convs_b[192 + oc] - bn_m[256 + oc]) * s + bn_b[256 + oc], 0.0f);
    }
  }
  gbar(ctr, 1280);

  // ---- stage D: avgpool + head + argmax (block 0, wave 0) ----
  if (blk == 0 && tid < 64) {
    float ssum = 0.0f;
#pragma unroll
    for (int k = 0; k < 64; ++k) ssum += c4[tid * 64 + k];
    const float feat = ssum * (1.0f / 64.0f);
    float p0 = feat * head_w[tid];
    float p1 = feat * head_w[64 + tid];
#pragma unroll
    for (int off = 32; off > 0; off >>= 1) {
      p0 += __shfl_down(p0, off);
      p1 += __shfl_down(p1, off);
    }
    if (tid == 0) {
      const float l0 = p0 + head_b[0];
      const float l1 = p1 + head_b[1];
      out[0] = (l1 > l0) ? 1.0f : 0.0f;
    }
  }
}

// ---------------------------------------------------------------------------
extern "C" void kernel_launch(void* const* d_in, const int* in_sizes, int n_in,
                              void* d_out, int out_size, void* d_ws,
                              size_t ws_size, hipStream_t stream) {
  const float* image   = (const float*)d_in[0];
  const float* conv0_w = (const float*)d_in[1];
  const float* conv0_b = (const float*)d_in[2];
  const float* convs_w = (const float*)d_in[3];  // [4][64][64][3][3]
  const float* convs_b = (const float*)d_in[4];  // [4][64]
  const float* bn_g    = (const float*)d_in[5];  // [5][64]
  const float* bn_b    = (const float*)d_in[6];
  const float* bn_m    = (const float*)d_in[7];
  const float* bn_v    = (const float*)d_in[8];
  const float* head_w  = (const float*)d_in[9];  // [2][64]
  const float* head_b  = (const float*)d_in[10]; // [2]

  // workspace layout (floats)
  float* W = (float*)d_ws;
  int* bounds = (int*)d_ws;            // 4 ints
  int* ctr = (int*)d_ws + 8;           // grid-barrier counter
  float* x1 = W + 16;                  // 256*256   (post dilate/invert)
  float* c0 = x1 + 65536;              // 64*128*128
  float* c1 = c0 + 1048576;            // 64*64*64
  float* c2 = c1 + 262144;             // 64*32*32
  float* c3 = c2 + 65536;              // 64*16*16
  float* c4 = c3 + 16384;              // 64*8*8
  float* p3 = c4 + 4096;               // 4*64*256
  float* p4 = p3 + 65536;              // 16*64*64

  crop_bounds_k<<<4, 256, 0, stream>>>(image, bounds, ctr);
  resize_dilate_k<<<256, 256, 0, stream>>>(image, bounds, x1);

  // conv0: 1 -> 64, 256 -> 128   (512 blocks, 8 oc/thread)
  conv_bn_relu_k<8><<<dim3(8, 8, 8), 256, 0, stream>>>(
      x1, conv0_w, conv0_b, bn_g, bn_b, bn_m, bn_v, c0, 1, 256, 256, 128, 128);
  // conv1: 64 -> 64, 128 -> 64   (512 blocks, 2 oc/thread -> 2 waves/SIMD)
  conv_bn_relu_k<2><<<dim3(4, 4, 32), 256, 0, stream>>>(
      c0, convs_w + 0 * 36864, convs_b + 0 * 64, bn_g + 64, bn_b + 64,
      bn_m + 64, bn_v + 64, c1, 64, 128, 128, 64, 64);

  // conv2 + conv3 + conv4 + head, fused with grid barriers (256 blocks)
  tail_fused_k<<<256, 256, 0, stream>>>(
      c1, convs_w, convs_b, bn_g, bn_b, bn_m, bn_v, head_w, head_b,
      c2, c3, c4, p3, p4, ctr, (float*)d_out);
}